// Round 2
// baseline (1423.836 us; speedup 1.0000x reference)
//
#include <hip/hip_runtime.h>

#define Bz 512
#define Tz 20
#define NOBJz 36
#define Dz 2048
#define EMBz 300
#define Ez 512
#define HMz 1024
#define HOz 256
#define KXM 832     // E + EMB = 812 padded to x64
#define KXO 1344    // 2E + EMB = 1324 padded to x64

typedef short v8s __attribute__((ext_vector_type(8)));
typedef float v4f __attribute__((ext_vector_type(4)));
typedef unsigned short u16;

__device__ __forceinline__ float sigf(float x) { return 1.f / (1.f + __expf(-x)); }
__device__ __forceinline__ float tanhfast(float x) { return 2.f * sigf(2.f * x) - 1.f; }

__device__ __forceinline__ u16 f2bf(float f) {
    union { float f; unsigned u; } v; v.f = f;
    unsigned u = v.u;
    u += 0x7FFFu + ((u >> 16) & 1u);   // RNE
    return (u16)(u >> 16);
}
__device__ __forceinline__ float bf2f(u16 h) {
    union { unsigned u; float f; } v; v.u = ((unsigned)h) << 16;
    return v.f;
}

// =================== prologue kernels ===================

// fused obj_mask + meanim: one block per batch row, obj_enc read once from HBM
__global__ __launch_bounds__(256) void meanim_fused(const float* __restrict__ obj_enc,
                                                    u16* __restrict__ meanim_bf) {
    const int b = blockIdx.x;
    const int tid = threadIdx.x, lane = tid & 63, w = tid >> 6;
    __shared__ float mask_s[NOBJz];
    // phase 1: per-object |.| sum -> mask
    for (int n = w; n < NOBJz; n += 4) {
        const float* row = obj_enc + ((size_t)b * NOBJz + n) * Dz;
        float s = 0.f;
        for (int d = lane; d < Dz; d += 64) s += fabsf(row[d]);
        for (int off = 32; off > 0; off >>= 1) s += __shfl_down(s, off);
        if (lane == 0) mask_s[n] = (s > 0.f) ? 1.f : 0.f;
    }
    __syncthreads();
    float cnt = 0.f;
#pragma unroll
    for (int n = 0; n < NOBJz; ++n) cnt += mask_s[n];
    const float inv = 1.f / fmaxf(cnt, 1e-9f);
    // phase 2: masked mean over objects (re-reads hit L2/L3)
    for (int d = tid; d < Dz; d += 256) {
        float s = 0.f;
#pragma unroll 4
        for (int n = 0; n < NOBJz; ++n)
            s += obj_enc[((size_t)b * NOBJz + n) * Dz + d] * mask_s[n];
        meanim_bf[(size_t)b * Dz + d] = f2bf(s * inv);
    }
}

// fp32 -> bf16 weight convert, optional column slice, zero pad, optional gate-interleave
// row permutation: dst row r' <- src row g*permH + u with g=(r'>>4)&3, u=(r'>>6)*16+(r'&15)
__global__ void convert_pad(u16* __restrict__ dst, const float* __restrict__ src,
                            int rows, int src_cols, int ld_src, int col0, int dst_ld, int permH) {
    int idx = blockIdx.x * 256 + threadIdx.x;
    if (idx >= rows * dst_ld) return;
    int rp = idx / dst_ld, c = idx - rp * dst_ld;
    int n = rp;
    if (permH) { int g = (rp >> 4) & 3, u = (rp >> 6) * 16 + (rp & 15); n = g * permH + u; }
    dst[idx] = (c < src_cols) ? f2bf(src[(size_t)n * ld_src + col0 + c]) : (u16)0;
}

__global__ void bias_perm(float* __restrict__ dst, const float* __restrict__ src, int H) {
    int r = blockIdx.x * 256 + threadIdx.x;
    if (r >= 4 * H) return;
    int g = (r >> 4) & 3, u = (r >> 6) * 16 + (r & 15);
    dst[r] = src[g * H + u];
}

__global__ void assemble_Xm(u16* __restrict__ X, const float* __restrict__ qzm,
                            const int* __restrict__ x, const float* __restrict__ emd) {
    int idx = blockIdx.x * 256 + threadIdx.x;
    if (idx >= Tz * Bz * KXM) return;
    int r = idx / KXM, c = idx - r * KXM;
    int t = r / Bz, b = r - t * Bz;
    float v;
    if (c < Ez)             v = (t > 0) ? qzm[((size_t)b * Tz + (t - 1)) * Ez + c] : 0.f;
    else if (c < Ez + EMBz) { int xv = x[b * Tz + t]; v = emd[(size_t)xv * EMBz + (c - Ez)]; }
    else                    v = 0.f;
    X[idx] = f2bf(v);
}

__global__ void assemble_Xo(u16* __restrict__ X, const float* __restrict__ qzm,
                            const float* __restrict__ qzo, const int* __restrict__ x,
                            const float* __restrict__ emd) {
    int idx = blockIdx.x * 256 + threadIdx.x;
    if (idx >= Tz * Bz * KXO) return;
    int r = idx / KXO, c = idx - r * KXO;
    int t = r / Bz, b = r - t * Bz;
    float v;
    if (c < Ez)                 v = qzm[((size_t)b * Tz + t) * Ez + c];
    else if (c < 2 * Ez)        v = (t > 0) ? qzo[((size_t)b * Tz + (t - 1)) * Ez + (c - Ez)] : 0.f;
    else if (c < 2 * Ez + EMBz) { int xv = x[b * Tz + t]; v = emd[(size_t)xv * EMBz + (c - 2 * Ez)]; }
    else                        v = 0.f;
    X[idx] = f2bf(v);
}

// =================== MFMA GEMM core ===================
// 128x128 tile, BK=64, global_load_lds, XOR swizzle, 2-phase stage-ahead double-buffer.
// LDS tile: 128 rows x 64 bf16, row-major stride 64; 8-elem chunk p of row r holds
// logical k-chunk (p ^ (r&7)).  Staged with global_load_lds width=16 (lane-contiguous).
// 4 waves as 2(M) x 2(N), each 64x64 via 4x4 MFMA 16x16x32 accumulators.

#define TILE_E (128 * 64)

__device__ __forceinline__ void stage128(const u16* __restrict__ gA, int lda,
                                         const u16* __restrict__ gW, int ldw,
                                         u16* __restrict__ As, u16* __restrict__ Ws,
                                         int w, int lrow, int lcol) {
#pragma unroll
    for (int c = 0; c < 4; ++c) {
        int chunk = w * 4 + c;              // 16 chunks of 8 rows each
        int row = chunk * 8 + lrow;
        __builtin_amdgcn_global_load_lds(
            (const __attribute__((address_space(1))) unsigned int*)(gA + (size_t)row * lda + lcol),
            (__attribute__((address_space(3))) unsigned int*)(As + chunk * 512), 16, 0, 0);
        __builtin_amdgcn_global_load_lds(
            (const __attribute__((address_space(1))) unsigned int*)(gW + (size_t)row * ldw + lcol),
            (__attribute__((address_space(3))) unsigned int*)(Ws + chunk * 512), 16, 0, 0);
    }
}

__device__ __forceinline__ void mma128(
    const u16* __restrict__ A, int lda, const u16* __restrict__ W, int ldw, int K,
    int bm, int bn, u16* As, u16* Ws, v4f (&acc)[4][4]) {
    const int tid = threadIdx.x;
    const int lane = tid & 63, w = tid >> 6;
    const int wm = w >> 1, wn = w & 1;
    const int r15 = lane & 15, quad = lane >> 4;
    const int lrow = lane >> 3;                 // 0..7 within chunk
    const int lcol = ((lane & 7) ^ lrow) * 8;   // swizzled source column (elements)
    const u16* gA = A + (size_t)bm * lda;
    const u16* gW = W + (size_t)bn * ldw;
    // prologue: stage first tile into buf 0
    stage128(gA, lda, gW, ldw, As, Ws, w, lrow, lcol);
    __syncthreads();
    int cur = 0;
    for (int k0 = 0; k0 < K; k0 += 64) {
        // issue next tile's loads BEFORE computing current (latency hides under MFMA)
        if (k0 + 64 < K)
            stage128(gA + k0 + 64, lda, gW + k0 + 64, ldw,
                     As + (cur ^ 1) * TILE_E, Ws + (cur ^ 1) * TILE_E, w, lrow, lcol);
        const u16* Asc = As + cur * TILE_E;
        const u16* Wsc = Ws + cur * TILE_E;
#pragma unroll
        for (int kk = 0; kk < 64; kk += 32) {
            v8s a[4], b[4];
#pragma unroll
            for (int i = 0; i < 4; ++i) {
                int r = wm * 64 + 16 * i + r15;
                a[i] = *(const v8s*)&Asc[r * 64 + (((kk >> 3) + quad) ^ (r15 & 7)) * 8];
            }
#pragma unroll
            for (int j = 0; j < 4; ++j) {
                int r = wn * 64 + 16 * j + r15;
                b[j] = *(const v8s*)&Wsc[r * 64 + (((kk >> 3) + quad) ^ (r15 & 7)) * 8];
            }
#pragma unroll
            for (int i = 0; i < 4; ++i)
#pragma unroll
                for (int j = 0; j < 4; ++j)
                    acc[i][j] = __builtin_amdgcn_mfma_f32_16x16x32_bf16(a[i], b[j], acc[i][j], 0, 0, 0);
        }
        __syncthreads();   // implicit vmcnt(0): next-tile loads complete; readers of cur done
        cur ^= 1;
    }
}

// generic GEMM: C(M,N) = A @ W^T (+bias[col]) (+addR bf16[row&mask][col]) ; out fp32 or bf16
__global__ __launch_bounds__(256) void gemm128(
    const u16* __restrict__ A, int lda, const u16* __restrict__ W, int ldw,
    void* __restrict__ Cv, int ldc, int K,
    const float* __restrict__ bias, const u16* __restrict__ addR, unsigned addR_mask, int out_bf16) {
    __shared__ u16 As[2 * TILE_E];
    __shared__ u16 Ws[2 * TILE_E];
    v4f acc[4][4] = {};
    const int bm = blockIdx.y * 128, bn = blockIdx.x * 128;
    mma128(A, lda, W, ldw, K, bm, bn, As, Ws, acc);
    const int tid = threadIdx.x, lane = tid & 63, w = tid >> 6;
    const int wm = w >> 1, wn = w & 1, r15 = lane & 15, quad = lane >> 4;
    float* Cf = (float*)Cv;
    u16* Cb = (u16*)Cv;
#pragma unroll
    for (int i = 0; i < 4; ++i)
#pragma unroll
        for (int j = 0; j < 4; ++j) {
            int col = bn + wn * 64 + 16 * j + r15;
            float bv = bias ? bias[col] : 0.f;
#pragma unroll
            for (int r = 0; r < 4; ++r) {
                int row = bm + wm * 64 + 16 * i + quad * 4 + r;
                float v = acc[i][j][r] + bv;
                if (addR) v += bf2f(addR[(size_t)(row & addR_mask) * ldc + col]);
                if (out_bf16) Cb[(size_t)row * ldc + col] = f2bf(v);
                else          Cf[(size_t)row * ldc + col] = v;
            }
        }
}

// fused step: g = h_prev @ Whh^T + Ginp(permuted), then LSTM cell in-register.
// Gate interleave means wave's j index IS the gate (i,f,g,o) for unit ((bn+wn*64)>>6)*16 + r15.
// blocks [0,128): mask LSTM (N=4096, K=1024); blocks [128,160): obj LSTM (N=1024, K=256)
__global__ __launch_bounds__(256) void step_fused(
    const u16* __restrict__ Hm_prev, const u16* __restrict__ Whh_m, const u16* __restrict__ Gm,
    float* __restrict__ cm, u16* __restrict__ hm,
    const u16* __restrict__ Ho_prev, const u16* __restrict__ Whh_o, const u16* __restrict__ Go,
    float* __restrict__ co, u16* __restrict__ ho) {
    __shared__ u16 As[2 * TILE_E];
    __shared__ u16 Ws[2 * TILE_E];
    v4f acc[4][4] = {};
    const int bx = blockIdx.x;
    const u16 *A, *W, *G;
    float* c;
    u16* h;
    int lda, N4, H, bm, bn, K;
    if (bx < 128) {
        bm = (bx >> 5) * 128; bn = (bx & 31) * 128;
        A = Hm_prev; W = Whh_m; G = Gm; c = cm; h = hm; lda = HMz; N4 = 4 * HMz; H = HMz; K = HMz;
    } else {
        int lx = bx - 128;
        bm = (lx >> 3) * 128; bn = (lx & 7) * 128;
        A = Ho_prev; W = Whh_o; G = Go; c = co; h = ho; lda = HOz; N4 = 4 * HOz; H = HOz; K = HOz;
    }
    mma128(A, lda, W, lda, K, bm, bn, As, Ws, acc);
    const int tid = threadIdx.x, lane = tid & 63, w = tid >> 6;
    const int wm = w >> 1, wn = w & 1, r15 = lane & 15, quad = lane >> 4;
    const int u = ((bn + wn * 64) >> 6) * 16 + r15;
#pragma unroll
    for (int i = 0; i < 4; ++i)
#pragma unroll
        for (int r = 0; r < 4; ++r) {
            int b = bm + wm * 64 + 16 * i + quad * 4 + r;
            size_t gb = (size_t)b * N4 + bn + wn * 64 + r15;
            float gi = acc[i][0][r] + bf2f(G[gb]);
            float gf = acc[i][1][r] + bf2f(G[gb + 16]);
            float gg = acc[i][2][r] + bf2f(G[gb + 32]);
            float go = acc[i][3][r] + bf2f(G[gb + 48]);
            size_t ci = (size_t)b * H + u;
            float cn = sigf(gf) * c[ci] + sigf(gi) * tanhfast(gg);
            c[ci] = cn;
            h[ci] = f2bf(sigf(go) * tanhfast(cn));
        }
}

// t=0 cell: gates = Ginp only (h_prev = 0, c_prev = 0); Ginp is gate-interleaved
__global__ void cell0(const u16* __restrict__ Gm, float* __restrict__ cm, u16* __restrict__ hm,
                      const u16* __restrict__ Go, float* __restrict__ co, u16* __restrict__ ho) {
    int idx = blockIdx.x * 256 + threadIdx.x;
    if (idx < Bz * HMz) {
        int b = idx / HMz, u = idx - b * HMz;
        size_t gb = (size_t)b * 4 * HMz + ((u >> 4) * 64 + (u & 15));
        float gi = bf2f(Gm[gb]), gf = bf2f(Gm[gb + 16]), gg = bf2f(Gm[gb + 32]), go = bf2f(Gm[gb + 48]);
        (void)gf;
        float cn = sigf(gi) * tanhfast(gg);
        cm[idx] = cn;
        hm[idx] = f2bf(sigf(go) * tanhfast(cn));
    } else {
        idx -= Bz * HMz;
        if (idx >= Bz * HOz) return;
        int b = idx / HOz, u = idx - b * HOz;
        size_t gb = (size_t)b * 4 * HOz + ((u >> 4) * 64 + (u & 15));
        float gi = bf2f(Go[gb]), gg = bf2f(Go[gb + 32]), go = bf2f(Go[gb + 48]);
        float cn = sigf(gi) * tanhfast(gg);
        co[idx] = cn;
        ho[idx] = f2bf(sigf(go) * tanhfast(cn));
    }
}

// =================== KL reduce ===================
__global__ __launch_bounds__(256) void kl_kernel(
    const float* __restrict__ outs_m, const float* __restrict__ outs_o,
    const float* __restrict__ qmm, const float* __restrict__ qlm,
    const float* __restrict__ qmo, const float* __restrict__ qlo,
    const int* __restrict__ x, float* __restrict__ out) {
    int b = blockIdx.x, tid = threadIdx.x;
    float total = 0.f;
    for (int t = 0; t < Tz; ++t) {
        int xv = x[b * Tz + t];
        if (xv == 0 || xv == 2) continue;
        const float* pm = outs_m + ((size_t)t * Bz + b) * 1024;
        const float* po = outs_o + ((size_t)t * Bz + b) * 1024;
        const size_t q = ((size_t)b * Tz + t) * Ez;
        for (int e = tid; e < Ez; e += 256) {
            float pmm = pm[e], plm = pm[Ez + e];
            float dm = qmm[q + e] - pmm;
            total += 0.5f * (plm - qlm[q + e]) + (__expf(qlm[q + e]) + dm * dm) / (2.f * __expf(plm)) - 0.5f;
            float pmo = po[e], plo = po[Ez + e];
            float dn = qmo[q + e] - pmo;
            total += 0.5f * (plo - qlo[q + e]) + (__expf(qlo[q + e]) + dn * dn) / (2.f * __expf(plo)) - 0.5f;
        }
    }
    __shared__ float red[256];
    red[tid] = total;
    __syncthreads();
    for (int s = 128; s > 0; s >>= 1) {
        if (tid < s) red[tid] += red[tid + s];
        __syncthreads();
    }
    if (tid == 0) out[b] = red[0];
}

extern "C" void kernel_launch(void* const* d_in, const int* in_sizes, int n_in,
                              void* d_out, int out_size, void* d_ws, size_t ws_size,
                              hipStream_t stream) {
    const float* obj_enc = (const float*)d_in[0];
    const int*   x       = (const int*)d_in[1];
    const float* qmm     = (const float*)d_in[2];
    const float* qlm     = (const float*)d_in[3];
    const float* qzm     = (const float*)d_in[4];
    const float* qmo     = (const float*)d_in[5];
    const float* qlo     = (const float*)d_in[6];
    const float* qzo     = (const float*)d_in[7];
    const float* emd     = (const float*)d_in[8];
    const float* W_ih_m  = (const float*)d_in[9];
    const float* W_hh_m  = (const float*)d_in[10];
    const float* b_m     = (const float*)d_in[11];
    const float* W_ih_o  = (const float*)d_in[12];
    const float* W_hh_o  = (const float*)d_in[13];
    const float* b_o     = (const float*)d_in[14];
    const float* fc_m_W  = (const float*)d_in[15];
    const float* fc_m_b  = (const float*)d_in[16];
    const float* fc_o_W  = (const float*)d_in[17];
    const float* fc_o_b  = (const float*)d_in[18];
    float* out = (float*)d_out;

    char* base = (char*)d_ws;
    size_t off = 0;
    auto alloc = [&](size_t bytes) { char* r = base + off; off += (bytes + 255) & ~(size_t)255; return r; };
    u16* meanim_bf  = (u16*)alloc((size_t)Bz * Dz * 2);
    u16* Whh_m_bf   = (u16*)alloc((size_t)4 * HMz * HMz * 2);
    u16* Whh_o_bf   = (u16*)alloc((size_t)4 * HOz * HOz * 2);
    u16* Winp_m_bf  = (u16*)alloc((size_t)4 * HMz * KXM * 2);
    u16* Winp_o_bf  = (u16*)alloc((size_t)4 * HOz * KXO * 2);
    u16* Wmean_m_bf = (u16*)alloc((size_t)4 * HMz * Dz * 2);
    u16* Wmean_o_bf = (u16*)alloc((size_t)4 * HOz * Dz * 2);
    u16* Wfc_m_bf   = (u16*)alloc((size_t)1024 * HMz * 2);
    u16* Wfc_o_bf   = (u16*)alloc((size_t)1024 * HOz * 2);
    float* b_m_p    = (float*)alloc((size_t)4 * HMz * 4);
    float* b_o_p    = (float*)alloc((size_t)4 * HOz * 4);
    u16* Xin_m      = (u16*)alloc((size_t)Tz * Bz * KXM * 2);
    u16* Xin_o      = (u16*)alloc((size_t)Tz * Bz * KXO * 2);
    u16* const_m_bf = (u16*)alloc((size_t)Bz * 4 * HMz * 2);
    u16* const_o_bf = (u16*)alloc((size_t)Bz * 4 * HOz * 2);
    u16* Ginp_m_bf  = (u16*)alloc((size_t)Tz * Bz * 4 * HMz * 2);   // aliased by outs after loop
    u16* Ginp_o_bf  = (u16*)alloc((size_t)Tz * Bz * 4 * HOz * 2);
    float* c_m      = (float*)alloc((size_t)Bz * HMz * 4);
    float* c_o      = (float*)alloc((size_t)Bz * HOz * 4);
    u16* H_m        = (u16*)alloc((size_t)Tz * Bz * HMz * 2);
    u16* H_o        = (u16*)alloc((size_t)Tz * Bz * HOz * 2);
    float* outs_m = (float*)Ginp_m_bf;                              // 2 x 41.9MB inside 83.9MB
    float* outs_o = outs_m + (size_t)Tz * Bz * 1024;

    const int TB = Tz * Bz;

    meanim_fused<<<Bz, 256, 0, stream>>>(obj_enc, meanim_bf);
    assemble_Xm<<<(TB * KXM + 255) / 256, 256, 0, stream>>>(Xin_m, qzm, x, emd);
    assemble_Xo<<<(TB * KXO + 255) / 256, 256, 0, stream>>>(Xin_o, qzm, qzo, x, emd);

    // weight conversions: LSTM weights get the gate-interleaved row permutation
    convert_pad<<<(4 * HMz * HMz + 255) / 256, 256, 0, stream>>>(Whh_m_bf, W_hh_m, 4 * HMz, HMz, HMz, 0, HMz, HMz);
    convert_pad<<<(4 * HOz * HOz + 255) / 256, 256, 0, stream>>>(Whh_o_bf, W_hh_o, 4 * HOz, HOz, HOz, 0, HOz, HOz);
    convert_pad<<<(4 * HMz * KXM + 255) / 256, 256, 0, stream>>>(Winp_m_bf, W_ih_m, 4 * HMz, Ez + EMBz, 2860, 0, KXM, HMz);
    convert_pad<<<(4 * HOz * KXO + 255) / 256, 256, 0, stream>>>(Winp_o_bf, W_ih_o, 4 * HOz, 2 * Ez + EMBz, 3372, 0, KXO, HOz);
    convert_pad<<<(4 * HMz * Dz + 255) / 256, 256, 0, stream>>>(Wmean_m_bf, W_ih_m, 4 * HMz, Dz, 2860, Ez + EMBz, Dz, HMz);
    convert_pad<<<(4 * HOz * Dz + 255) / 256, 256, 0, stream>>>(Wmean_o_bf, W_ih_o, 4 * HOz, Dz, 3372, 2 * Ez + EMBz, Dz, HOz);
    convert_pad<<<(1024 * HMz + 255) / 256, 256, 0, stream>>>(Wfc_m_bf, fc_m_W, 1024, HMz, HMz, 0, HMz, 0);
    convert_pad<<<(1024 * HOz + 255) / 256, 256, 0, stream>>>(Wfc_o_bf, fc_o_W, 1024, HOz, HOz, 0, HOz, 0);
    bias_perm<<<(4 * HMz + 255) / 256, 256, 0, stream>>>(b_m_p, b_m, HMz);
    bias_perm<<<(4 * HOz + 255) / 256, 256, 0, stream>>>(b_o_p, b_o, HOz);

    // const = bias + meanim projection (bf16, gate-interleaved cols)
    gemm128<<<dim3(4 * HMz / 128, Bz / 128), 256, 0, stream>>>(
        meanim_bf, Dz, Wmean_m_bf, Dz, const_m_bf, 4 * HMz, Dz, b_m_p, nullptr, 0u, 1);
    gemm128<<<dim3(4 * HOz / 128, Bz / 128), 256, 0, stream>>>(
        meanim_bf, Dz, Wmean_o_bf, Dz, const_o_bf, 4 * HOz, Dz, b_o_p, nullptr, 0u, 1);

    // Ginp = Xin @ Winp^T + const  (all T at once; addR row = global row & 511 = b)
    gemm128<<<dim3(4 * HMz / 128, TB / 128), 256, 0, stream>>>(
        Xin_m, KXM, Winp_m_bf, KXM, Ginp_m_bf, 4 * HMz, KXM, nullptr, const_m_bf, (unsigned)(Bz - 1), 1);
    gemm128<<<dim3(4 * HOz / 128, TB / 128), 256, 0, stream>>>(
        Xin_o, KXO, Winp_o_bf, KXO, Ginp_o_bf, 4 * HOz, KXO, nullptr, const_o_bf, (unsigned)(Bz - 1), 1);

    // t = 0: gates are Ginp only
    cell0<<<(Bz * (HMz + HOz) + 255) / 256, 256, 0, stream>>>(
        Ginp_m_bf, c_m, H_m, Ginp_o_bf, c_o, H_o);

    // t = 1..19: one fused GEMM+cell launch per step (mask: 128 blocks, obj: 32 blocks)
    for (int t = 1; t < Tz; ++t) {
        step_fused<<<160, 256, 0, stream>>>(
            H_m + (size_t)(t - 1) * Bz * HMz, Whh_m_bf, Ginp_m_bf + (size_t)t * Bz * 4 * HMz,
            c_m, H_m + (size_t)t * Bz * HMz,
            H_o + (size_t)(t - 1) * Bz * HOz, Whh_o_bf, Ginp_o_bf + (size_t)t * Bz * 4 * HOz,
            c_o, H_o + (size_t)t * Bz * HOz);
    }

    // FC heads over all (t,b) rows (normal column order, fp32 out)
    gemm128<<<dim3(1024 / 128, TB / 128), 256, 0, stream>>>(
        H_m, HMz, Wfc_m_bf, HMz, outs_m, 1024, HMz, fc_m_b, nullptr, 0u, 0);
    gemm128<<<dim3(1024 / 128, TB / 128), 256, 0, stream>>>(
        H_o, HOz, Wfc_o_bf, HOz, outs_o, 1024, HOz, fc_o_b, nullptr, 0u, 0);

    kl_kernel<<<Bz, 256, 0, stream>>>(outs_m, outs_o, qmm, qlm, qmo, qlo, x, out);
}

// Round 3
// 1159.153 us; speedup vs baseline: 1.2283x; 1.2283x over previous
//
#include <hip/hip_runtime.h>

#define Bz 512
#define Tz 20
#define NOBJz 36
#define Dz 2048
#define EMBz 300
#define Ez 512
#define HMz 1024
#define HOz 256
#define KXM 832     // E + EMB = 812 padded to x64
#define KXO 1344    // 2E + EMB = 1324 padded to x64

typedef short v8s __attribute__((ext_vector_type(8)));
typedef float v4f __attribute__((ext_vector_type(4)));
typedef unsigned short u16;

__device__ __forceinline__ float sigf(float x) { return 1.f / (1.f + __expf(-x)); }
__device__ __forceinline__ float tanhfast(float x) { return 2.f * sigf(2.f * x) - 1.f; }

__device__ __forceinline__ u16 f2bf(float f) {
    union { float f; unsigned u; } v; v.f = f;
    unsigned u = v.u;
    u += 0x7FFFu + ((u >> 16) & 1u);   // RNE
    return (u16)(u >> 16);
}
__device__ __forceinline__ float bf2f(u16 h) {
    union { unsigned u; float f; } v; v.u = ((unsigned)h) << 16;
    return v.f;
}

// =================== prologue kernels ===================

// one wave per (b,n) row: streams obj_enc once from HBM at high parallelism
__global__ void obj_mask_kernel(const float* __restrict__ obj_enc, float* __restrict__ mask) {
    int bn = blockIdx.x, lane = threadIdx.x;
    const v4f* row = (const v4f*)(obj_enc + (size_t)bn * Dz);
    float s = 0.f;
    for (int d = lane; d < Dz / 4; d += 64) {
        v4f v = row[d];
        s += fabsf(v[0]) + fabsf(v[1]) + fabsf(v[2]) + fabsf(v[3]);
    }
    for (int off = 32; off > 0; off >>= 1) s += __shfl_down(s, off);
    if (lane == 0) mask[bn] = (s > 0.f) ? 1.f : 0.f;
}

// one float4 of d per thread; obj_enc re-read hits L3 (151 MB < 256 MB)
__global__ __launch_bounds__(256) void meanim_kernel(const float* __restrict__ obj_enc,
                                                     const float* __restrict__ mask,
                                                     u16* __restrict__ meanim_bf) {
    int idx = blockIdx.x * 256 + threadIdx.x;
    if (idx >= Bz * (Dz / 4)) return;
    int b = idx / (Dz / 4), d4 = idx - b * (Dz / 4);
    const float* mrow = mask + b * NOBJz;
    v4f s = {0.f, 0.f, 0.f, 0.f};
    float cnt = 0.f;
#pragma unroll 4
    for (int n = 0; n < NOBJz; ++n) {
        float m = mrow[n];
        cnt += m;
        v4f v = *(const v4f*)(obj_enc + ((size_t)b * NOBJz + n) * Dz + d4 * 4);
        s[0] += v[0] * m; s[1] += v[1] * m; s[2] += v[2] * m; s[3] += v[3] * m;
    }
    float inv = 1.f / fmaxf(cnt, 1e-9f);
    u16 o[4] = {f2bf(s[0] * inv), f2bf(s[1] * inv), f2bf(s[2] * inv), f2bf(s[3] * inv)};
    *(uint2*)&meanim_bf[(size_t)b * Dz + d4 * 4] = *(const uint2*)o;
}

// fp32 -> bf16 weight convert, optional column slice, zero pad, optional gate-interleave
// row permutation: dst row r' <- src row g*permH + u with g=(r'>>4)&3, u=(r'>>6)*16+(r'&15)
__global__ void convert_pad(u16* __restrict__ dst, const float* __restrict__ src,
                            int rows, int src_cols, int ld_src, int col0, int dst_ld, int permH) {
    int idx = blockIdx.x * 256 + threadIdx.x;
    if (idx >= rows * dst_ld) return;
    int rp = idx / dst_ld, c = idx - rp * dst_ld;
    int n = rp;
    if (permH) { int g = (rp >> 4) & 3, u = (rp >> 6) * 16 + (rp & 15); n = g * permH + u; }
    dst[idx] = (c < src_cols) ? f2bf(src[(size_t)n * ld_src + col0 + c]) : (u16)0;
}

__global__ void bias_perm(float* __restrict__ dst, const float* __restrict__ src, int H) {
    int r = blockIdx.x * 256 + threadIdx.x;
    if (r >= 4 * H) return;
    int g = (r >> 4) & 3, u = (r >> 6) * 16 + (r & 15);
    dst[r] = src[g * H + u];
}

__global__ void assemble_Xm(u16* __restrict__ X, const float* __restrict__ qzm,
                            const int* __restrict__ x, const float* __restrict__ emd) {
    int idx = blockIdx.x * 256 + threadIdx.x;
    if (idx >= Tz * Bz * KXM) return;
    int r = idx / KXM, c = idx - r * KXM;
    int t = r / Bz, b = r - t * Bz;
    float v;
    if (c < Ez)             v = (t > 0) ? qzm[((size_t)b * Tz + (t - 1)) * Ez + c] : 0.f;
    else if (c < Ez + EMBz) { int xv = x[b * Tz + t]; v = emd[(size_t)xv * EMBz + (c - Ez)]; }
    else                    v = 0.f;
    X[idx] = f2bf(v);
}

__global__ void assemble_Xo(u16* __restrict__ X, const float* __restrict__ qzm,
                            const float* __restrict__ qzo, const int* __restrict__ x,
                            const float* __restrict__ emd) {
    int idx = blockIdx.x * 256 + threadIdx.x;
    if (idx >= Tz * Bz * KXO) return;
    int r = idx / KXO, c = idx - r * KXO;
    int t = r / Bz, b = r - t * Bz;
    float v;
    if (c < Ez)                 v = qzm[((size_t)b * Tz + t) * Ez + c];
    else if (c < 2 * Ez)        v = (t > 0) ? qzo[((size_t)b * Tz + (t - 1)) * Ez + (c - Ez)] : 0.f;
    else if (c < 2 * Ez + EMBz) { int xv = x[b * Tz + t]; v = emd[(size_t)xv * EMBz + (c - 2 * Ez)]; }
    else                        v = 0.f;
    X[idx] = f2bf(v);
}

// =================== MFMA GEMM core (128x128 tile) ===================
// LDS tile: 128 rows x 64 bf16, row-major stride 64; 8-elem chunk p of row r holds
// logical k-chunk (p ^ (r&7)).  Staged with global_load_lds width=16 (lane-contiguous).
// 4 waves as 2(M) x 2(N), each 64x64 via 4x4 MFMA 16x16x32 accumulators.
// 2-phase stage-ahead double-buffer.

#define TILE_E (128 * 64)

__device__ __forceinline__ void stage128(const u16* __restrict__ gA, int lda,
                                         const u16* __restrict__ gW, int ldw,
                                         u16* __restrict__ As, u16* __restrict__ Ws,
                                         int w, int lrow, int lcol) {
#pragma unroll
    for (int c = 0; c < 4; ++c) {
        int chunk = w * 4 + c;              // 16 chunks of 8 rows each
        int row = chunk * 8 + lrow;
        __builtin_amdgcn_global_load_lds(
            (const __attribute__((address_space(1))) unsigned int*)(gA + (size_t)row * lda + lcol),
            (__attribute__((address_space(3))) unsigned int*)(As + chunk * 512), 16, 0, 0);
        __builtin_amdgcn_global_load_lds(
            (const __attribute__((address_space(1))) unsigned int*)(gW + (size_t)row * ldw + lcol),
            (__attribute__((address_space(3))) unsigned int*)(Ws + chunk * 512), 16, 0, 0);
    }
}

__device__ __forceinline__ void mma128(
    const u16* __restrict__ A, int lda, const u16* __restrict__ W, int ldw, int K,
    int bm, int bn, u16* As, u16* Ws, v4f (&acc)[4][4]) {
    const int tid = threadIdx.x;
    const int lane = tid & 63, w = tid >> 6;
    const int wm = w >> 1, wn = w & 1;
    const int r15 = lane & 15, quad = lane >> 4;
    const int lrow = lane >> 3;                 // 0..7 within chunk
    const int lcol = ((lane & 7) ^ lrow) * 8;   // swizzled source column (elements)
    const u16* gA = A + (size_t)bm * lda;
    const u16* gW = W + (size_t)bn * ldw;
    stage128(gA, lda, gW, ldw, As, Ws, w, lrow, lcol);
    __syncthreads();
    int cur = 0;
    for (int k0 = 0; k0 < K; k0 += 64) {
        if (k0 + 64 < K)
            stage128(gA + k0 + 64, lda, gW + k0 + 64, ldw,
                     As + (cur ^ 1) * TILE_E, Ws + (cur ^ 1) * TILE_E, w, lrow, lcol);
        const u16* Asc = As + cur * TILE_E;
        const u16* Wsc = Ws + cur * TILE_E;
#pragma unroll
        for (int kk = 0; kk < 64; kk += 32) {
            v8s a[4], b[4];
#pragma unroll
            for (int i = 0; i < 4; ++i) {
                int r = wm * 64 + 16 * i + r15;
                a[i] = *(const v8s*)&Asc[r * 64 + (((kk >> 3) + quad) ^ (r15 & 7)) * 8];
            }
#pragma unroll
            for (int j = 0; j < 4; ++j) {
                int r = wn * 64 + 16 * j + r15;
                b[j] = *(const v8s*)&Wsc[r * 64 + (((kk >> 3) + quad) ^ (r15 & 7)) * 8];
            }
#pragma unroll
            for (int i = 0; i < 4; ++i)
#pragma unroll
                for (int j = 0; j < 4; ++j)
                    acc[i][j] = __builtin_amdgcn_mfma_f32_16x16x32_bf16(a[i], b[j], acc[i][j], 0, 0, 0);
        }
        __syncthreads();
        cur ^= 1;
    }
}

// generic GEMM: C(M,N) = A @ W^T (+bias[col]) (+addR bf16[row&mask][col]) ; out fp32 or bf16
__global__ __launch_bounds__(256) void gemm128(
    const u16* __restrict__ A, int lda, const u16* __restrict__ W, int ldw,
    void* __restrict__ Cv, int ldc, int K,
    const float* __restrict__ bias, const u16* __restrict__ addR, unsigned addR_mask, int out_bf16) {
    __shared__ u16 As[2 * TILE_E];
    __shared__ u16 Ws[2 * TILE_E];
    v4f acc[4][4] = {};
    const int bm = blockIdx.y * 128, bn = blockIdx.x * 128;
    mma128(A, lda, W, ldw, K, bm, bn, As, Ws, acc);
    const int tid = threadIdx.x, lane = tid & 63, w = tid >> 6;
    const int wm = w >> 1, wn = w & 1, r15 = lane & 15, quad = lane >> 4;
    float* Cf = (float*)Cv;
    u16* Cb = (u16*)Cv;
#pragma unroll
    for (int i = 0; i < 4; ++i)
#pragma unroll
        for (int j = 0; j < 4; ++j) {
            int col = bn + wn * 64 + 16 * j + r15;
            float bv = bias ? bias[col] : 0.f;
#pragma unroll
            for (int r = 0; r < 4; ++r) {
                int row = bm + wm * 64 + 16 * i + quad * 4 + r;
                float v = acc[i][j][r] + bv;
                if (addR) v += bf2f(addR[(size_t)(row & addR_mask) * ldc + col]);
                if (out_bf16) Cb[(size_t)row * ldc + col] = f2bf(v);
                else          Cf[(size_t)row * ldc + col] = v;
            }
        }
}

// =================== 64x64 MFMA core for the recurrent step ===================
// Same LDS layout/swizzle as mma128 but 64 rows per tile (8 chunks), 4 waves as
// 4(M) x 1(N): wave tile 16x64 -> acc[4] (j = gate), so each thread holds all
// 4 gates of its unit.  32 KB LDS (dbuf) -> high blocks/CU for latency hiding.

#define TILE64_E (64 * 64)

__device__ __forceinline__ void stage64(const u16* __restrict__ gA, int lda,
                                        const u16* __restrict__ gW, int ldw,
                                        u16* __restrict__ As, u16* __restrict__ Ws,
                                        int w, int lrow, int lcol) {
#pragma unroll
    for (int c = 0; c < 2; ++c) {
        int chunk = w * 2 + c;              // 8 chunks of 8 rows each
        int row = chunk * 8 + lrow;
        __builtin_amdgcn_global_load_lds(
            (const __attribute__((address_space(1))) unsigned int*)(gA + (size_t)row * lda + lcol),
            (__attribute__((address_space(3))) unsigned int*)(As + chunk * 512), 16, 0, 0);
        __builtin_amdgcn_global_load_lds(
            (const __attribute__((address_space(1))) unsigned int*)(gW + (size_t)row * ldw + lcol),
            (__attribute__((address_space(3))) unsigned int*)(Ws + chunk * 512), 16, 0, 0);
    }
}

__device__ __forceinline__ void mma64(
    const u16* __restrict__ A, int lda, const u16* __restrict__ W, int ldw, int K,
    int bm, int bn, u16* As, u16* Ws, v4f (&acc)[4]) {
    const int tid = threadIdx.x;
    const int lane = tid & 63, w = tid >> 6;
    const int r15 = lane & 15, quad = lane >> 4;
    const int lrow = lane >> 3;
    const int lcol = ((lane & 7) ^ lrow) * 8;
    const u16* gA = A + (size_t)bm * lda;
    const u16* gW = W + (size_t)bn * ldw;
    stage64(gA, lda, gW, ldw, As, Ws, w, lrow, lcol);
    __syncthreads();
    int cur = 0;
    for (int k0 = 0; k0 < K; k0 += 64) {
        if (k0 + 64 < K)
            stage64(gA + k0 + 64, lda, gW + k0 + 64, ldw,
                    As + (cur ^ 1) * TILE64_E, Ws + (cur ^ 1) * TILE64_E, w, lrow, lcol);
        const u16* Asc = As + cur * TILE64_E;
        const u16* Wsc = Ws + cur * TILE64_E;
#pragma unroll
        for (int kk = 0; kk < 64; kk += 32) {
            const int slot = ((kk >> 3) + quad) ^ (r15 & 7);
            v8s a, b[4];
            { int r = w * 16 + r15; a = *(const v8s*)&Asc[r * 64 + slot * 8]; }
#pragma unroll
            for (int j = 0; j < 4; ++j) {
                int r = 16 * j + r15;
                b[j] = *(const v8s*)&Wsc[r * 64 + slot * 8];
            }
#pragma unroll
            for (int j = 0; j < 4; ++j)
                acc[j] = __builtin_amdgcn_mfma_f32_16x16x32_bf16(a, b[j], acc[j], 0, 0, 0);
        }
        __syncthreads();
        cur ^= 1;
    }
}

// fused step on 64x64 tiles: g = h_prev @ Whh^T + Ginp(permuted), then LSTM cell.
// blocks [0,512): mask LSTM (8 bm x 64 bn); blocks [512,640): obj LSTM (8 bm x 16 bn)
__global__ __launch_bounds__(256) void step_fused64(
    const u16* __restrict__ Hm_prev, const u16* __restrict__ Whh_m, const u16* __restrict__ Gm,
    float* __restrict__ cm, u16* __restrict__ hm,
    const u16* __restrict__ Ho_prev, const u16* __restrict__ Whh_o, const u16* __restrict__ Go,
    float* __restrict__ co, u16* __restrict__ ho) {
    __shared__ u16 As[2 * TILE64_E];
    __shared__ u16 Ws[2 * TILE64_E];
    v4f acc[4] = {};
    const int bx = blockIdx.x;
    const u16 *A, *W, *G;
    float* c;
    u16* h;
    int lda, N4, H, bm, bn, K;
    if (bx < 512) {
        bm = (bx >> 6) * 64; bn = (bx & 63) * 64;
        A = Hm_prev; W = Whh_m; G = Gm; c = cm; h = hm; lda = HMz; N4 = 4 * HMz; H = HMz; K = HMz;
    } else {
        int lx = bx - 512;
        bm = (lx >> 4) * 64; bn = (lx & 15) * 64;
        A = Ho_prev; W = Whh_o; G = Go; c = co; h = ho; lda = HOz; N4 = 4 * HOz; H = HOz; K = HOz;
    }
    mma64(A, lda, W, lda, K, bm, bn, As, Ws, acc);
    const int tid = threadIdx.x, lane = tid & 63, w = tid >> 6;
    const int r15 = lane & 15, quad = lane >> 4;
    const int u = (bn >> 6) * 16 + r15;       // bn is a multiple of 64: one gate-group per tile
#pragma unroll
    for (int r = 0; r < 4; ++r) {
        int bidx = bm + w * 16 + quad * 4 + r;
        size_t gb = (size_t)bidx * N4 + bn + r15;
        float gi = acc[0][r] + bf2f(G[gb]);
        float gf = acc[1][r] + bf2f(G[gb + 16]);
        float gg = acc[2][r] + bf2f(G[gb + 32]);
        float go = acc[3][r] + bf2f(G[gb + 48]);
        size_t ci = (size_t)bidx * H + u;
        float cn = sigf(gf) * c[ci] + sigf(gi) * tanhfast(gg);
        c[ci] = cn;
        h[ci] = f2bf(sigf(go) * tanhfast(cn));
    }
}

// t=0 cell: gates = Ginp only (h_prev = 0, c_prev = 0); Ginp is gate-interleaved
__global__ void cell0(const u16* __restrict__ Gm, float* __restrict__ cm, u16* __restrict__ hm,
                      const u16* __restrict__ Go, float* __restrict__ co, u16* __restrict__ ho) {
    int idx = blockIdx.x * 256 + threadIdx.x;
    if (idx < Bz * HMz) {
        int b = idx / HMz, u = idx - b * HMz;
        size_t gb = (size_t)b * 4 * HMz + ((u >> 4) * 64 + (u & 15));
        float gi = bf2f(Gm[gb]), gg = bf2f(Gm[gb + 32]), go = bf2f(Gm[gb + 48]);
        float cn = sigf(gi) * tanhfast(gg);
        cm[idx] = cn;
        hm[idx] = f2bf(sigf(go) * tanhfast(cn));
    } else {
        idx -= Bz * HMz;
        if (idx >= Bz * HOz) return;
        int b = idx / HOz, u = idx - b * HOz;
        size_t gb = (size_t)b * 4 * HOz + ((u >> 4) * 64 + (u & 15));
        float gi = bf2f(Go[gb]), gg = bf2f(Go[gb + 32]), go = bf2f(Go[gb + 48]);
        float cn = sigf(gi) * tanhfast(gg);
        co[idx] = cn;
        ho[idx] = f2bf(sigf(go) * tanhfast(cn));
    }
}

// =================== KL reduce ===================
__global__ __launch_bounds__(256) void kl_kernel(
    const float* __restrict__ outs_m, const float* __restrict__ outs_o,
    const float* __restrict__ qmm, const float* __restrict__ qlm,
    const float* __restrict__ qmo, const float* __restrict__ qlo,
    const int* __restrict__ x, float* __restrict__ out) {
    int b = blockIdx.x, tid = threadIdx.x;
    float total = 0.f;
    for (int t = 0; t < Tz; ++t) {
        int xv = x[b * Tz + t];
        if (xv == 0 || xv == 2) continue;
        const float* pm = outs_m + ((size_t)t * Bz + b) * 1024;
        const float* po = outs_o + ((size_t)t * Bz + b) * 1024;
        const size_t q = ((size_t)b * Tz + t) * Ez;
        for (int e = tid; e < Ez; e += 256) {
            float pmm = pm[e], plm = pm[Ez + e];
            float dm = qmm[q + e] - pmm;
            total += 0.5f * (plm - qlm[q + e]) + (__expf(qlm[q + e]) + dm * dm) / (2.f * __expf(plm)) - 0.5f;
            float pmo = po[e], plo = po[Ez + e];
            float dn = qmo[q + e] - pmo;
            total += 0.5f * (plo - qlo[q + e]) + (__expf(qlo[q + e]) + dn * dn) / (2.f * __expf(plo)) - 0.5f;
        }
    }
    __shared__ float red[256];
    red[tid] = total;
    __syncthreads();
    for (int s = 128; s > 0; s >>= 1) {
        if (tid < s) red[tid] += red[tid + s];
        __syncthreads();
    }
    if (tid == 0) out[b] = red[0];
}

extern "C" void kernel_launch(void* const* d_in, const int* in_sizes, int n_in,
                              void* d_out, int out_size, void* d_ws, size_t ws_size,
                              hipStream_t stream) {
    const float* obj_enc = (const float*)d_in[0];
    const int*   x       = (const int*)d_in[1];
    const float* qmm     = (const float*)d_in[2];
    const float* qlm     = (const float*)d_in[3];
    const float* qzm     = (const float*)d_in[4];
    const float* qmo     = (const float*)d_in[5];
    const float* qlo     = (const float*)d_in[6];
    const float* qzo     = (const float*)d_in[7];
    const float* emd     = (const float*)d_in[8];
    const float* W_ih_m  = (const float*)d_in[9];
    const float* W_hh_m  = (const float*)d_in[10];
    const float* b_m     = (const float*)d_in[11];
    const float* W_ih_o  = (const float*)d_in[12];
    const float* W_hh_o  = (const float*)d_in[13];
    const float* b_o     = (const float*)d_in[14];
    const float* fc_m_W  = (const float*)d_in[15];
    const float* fc_m_b  = (const float*)d_in[16];
    const float* fc_o_W  = (const float*)d_in[17];
    const float* fc_o_b  = (const float*)d_in[18];
    float* out = (float*)d_out;

    char* base = (char*)d_ws;
    size_t off = 0;
    auto alloc = [&](size_t bytes) { char* r = base + off; off += (bytes + 255) & ~(size_t)255; return r; };
    float* mask     = (float*)alloc((size_t)Bz * NOBJz * 4);
    u16* meanim_bf  = (u16*)alloc((size_t)Bz * Dz * 2);
    u16* Whh_m_bf   = (u16*)alloc((size_t)4 * HMz * HMz * 2);
    u16* Whh_o_bf   = (u16*)alloc((size_t)4 * HOz * HOz * 2);
    u16* Winp_m_bf  = (u16*)alloc((size_t)4 * HMz * KXM * 2);
    u16* Winp_o_bf  = (u16*)alloc((size_t)4 * HOz * KXO * 2);
    u16* Wmean_m_bf = (u16*)alloc((size_t)4 * HMz * Dz * 2);
    u16* Wmean_o_bf = (u16*)alloc((size_t)4 * HOz * Dz * 2);
    u16* Wfc_m_bf   = (u16*)alloc((size_t)1024 * HMz * 2);
    u16* Wfc_o_bf   = (u16*)alloc((size_t)1024 * HOz * 2);
    float* b_m_p    = (float*)alloc((size_t)4 * HMz * 4);
    float* b_o_p    = (float*)alloc((size_t)4 * HOz * 4);
    u16* Xin_m      = (u16*)alloc((size_t)Tz * Bz * KXM * 2);
    u16* Xin_o      = (u16*)alloc((size_t)Tz * Bz * KXO * 2);
    u16* const_m_bf = (u16*)alloc((size_t)Bz * 4 * HMz * 2);
    u16* const_o_bf = (u16*)alloc((size_t)Bz * 4 * HOz * 2);
    u16* Ginp_m_bf  = (u16*)alloc((size_t)Tz * Bz * 4 * HMz * 2);   // aliased by outs after loop
    u16* Ginp_o_bf  = (u16*)alloc((size_t)Tz * Bz * 4 * HOz * 2);
    float* c_m      = (float*)alloc((size_t)Bz * HMz * 4);
    float* c_o      = (float*)alloc((size_t)Bz * HOz * 4);
    u16* H_m        = (u16*)alloc((size_t)Tz * Bz * HMz * 2);
    u16* H_o        = (u16*)alloc((size_t)Tz * Bz * HOz * 2);
    float* outs_m = (float*)Ginp_m_bf;                              // 2 x 41.9MB inside 83.9MB
    float* outs_o = outs_m + (size_t)Tz * Bz * 1024;

    const int TB = Tz * Bz;

    obj_mask_kernel<<<Bz * NOBJz, 64, 0, stream>>>(obj_enc, mask);
    meanim_kernel<<<(Bz * (Dz / 4) + 255) / 256, 256, 0, stream>>>(obj_enc, mask, meanim_bf);
    assemble_Xm<<<(TB * KXM + 255) / 256, 256, 0, stream>>>(Xin_m, qzm, x, emd);
    assemble_Xo<<<(TB * KXO + 255) / 256, 256, 0, stream>>>(Xin_o, qzm, qzo, x, emd);

    // weight conversions: LSTM weights get the gate-interleaved row permutation
    convert_pad<<<(4 * HMz * HMz + 255) / 256, 256, 0, stream>>>(Whh_m_bf, W_hh_m, 4 * HMz, HMz, HMz, 0, HMz, HMz);
    convert_pad<<<(4 * HOz * HOz + 255) / 256, 256, 0, stream>>>(Whh_o_bf, W_hh_o, 4 * HOz, HOz, HOz, 0, HOz, HOz);
    convert_pad<<<(4 * HMz * KXM + 255) / 256, 256, 0, stream>>>(Winp_m_bf, W_ih_m, 4 * HMz, Ez + EMBz, 2860, 0, KXM, HMz);
    convert_pad<<<(4 * HOz * KXO + 255) / 256, 256, 0, stream>>>(Winp_o_bf, W_ih_o, 4 * HOz, 2 * Ez + EMBz, 3372, 0, KXO, HOz);
    convert_pad<<<(4 * HMz * Dz + 255) / 256, 256, 0, stream>>>(Wmean_m_bf, W_ih_m, 4 * HMz, Dz, 2860, Ez + EMBz, Dz, HMz);
    convert_pad<<<(4 * HOz * Dz + 255) / 256, 256, 0, stream>>>(Wmean_o_bf, W_ih_o, 4 * HOz, Dz, 3372, 2 * Ez + EMBz, Dz, HOz);
    convert_pad<<<(1024 * HMz + 255) / 256, 256, 0, stream>>>(Wfc_m_bf, fc_m_W, 1024, HMz, HMz, 0, HMz, 0);
    convert_pad<<<(1024 * HOz + 255) / 256, 256, 0, stream>>>(Wfc_o_bf, fc_o_W, 1024, HOz, HOz, 0, HOz, 0);
    bias_perm<<<(4 * HMz + 255) / 256, 256, 0, stream>>>(b_m_p, b_m, HMz);
    bias_perm<<<(4 * HOz + 255) / 256, 256, 0, stream>>>(b_o_p, b_o, HOz);

    // const = bias + meanim projection (bf16, gate-interleaved cols)
    gemm128<<<dim3(4 * HMz / 128, Bz / 128), 256, 0, stream>>>(
        meanim_bf, Dz, Wmean_m_bf, Dz, const_m_bf, 4 * HMz, Dz, b_m_p, nullptr, 0u, 1);
    gemm128<<<dim3(4 * HOz / 128, Bz / 128), 256, 0, stream>>>(
        meanim_bf, Dz, Wmean_o_bf, Dz, const_o_bf, 4 * HOz, Dz, b_o_p, nullptr, 0u, 1);

    // Ginp = Xin @ Winp^T + const  (all T at once; addR row = global row & 511 = b)
    gemm128<<<dim3(4 * HMz / 128, TB / 128), 256, 0, stream>>>(
        Xin_m, KXM, Winp_m_bf, KXM, Ginp_m_bf, 4 * HMz, KXM, nullptr, const_m_bf, (unsigned)(Bz - 1), 1);
    gemm128<<<dim3(4 * HOz / 128, TB / 128), 256, 0, stream>>>(
        Xin_o, KXO, Winp_o_bf, KXO, Ginp_o_bf, 4 * HOz, KXO, nullptr, const_o_bf, (unsigned)(Bz - 1), 1);

    // t = 0: gates are Ginp only
    cell0<<<(Bz * (HMz + HOz) + 255) / 256, 256, 0, stream>>>(
        Ginp_m_bf, c_m, H_m, Ginp_o_bf, c_o, H_o);

    // t = 1..19: one fused GEMM+cell launch per step (mask: 512 blocks, obj: 128 blocks)
    for (int t = 1; t < Tz; ++t) {
        step_fused64<<<640, 256, 0, stream>>>(
            H_m + (size_t)(t - 1) * Bz * HMz, Whh_m_bf, Ginp_m_bf + (size_t)t * Bz * 4 * HMz,
            c_m, H_m + (size_t)t * Bz * HMz,
            H_o + (size_t)(t - 1) * Bz * HOz, Whh_o_bf, Ginp_o_bf + (size_t)t * Bz * 4 * HOz,
            c_o, H_o + (size_t)t * Bz * HOz);
    }

    // FC heads over all (t,b) rows (normal column order, fp32 out)
    gemm128<<<dim3(1024 / 128, TB / 128), 256, 0, stream>>>(
        H_m, HMz, Wfc_m_bf, HMz, outs_m, 1024, HMz, fc_m_b, nullptr, 0u, 0);
    gemm128<<<dim3(1024 / 128, TB / 128), 256, 0, stream>>>(
        H_o, HOz, Wfc_o_bf, HOz, outs_o, 1024, HOz, fc_o_b, nullptr, 0u, 0);

    kl_kernel<<<Bz, 256, 0, stream>>>(outs_m, outs_o, qmm, qlm, qmo, qlo, x, out);
}